// Round 1
// baseline (251.980 us; speedup 1.0000x reference)
//
#include <hip/hip_runtime.h>
#include <math.h>

#define T_TOTAL 16384
#define HDIM    2048
#define NEXP    64
#define KS      4                   // K-split factor
#define KSLICE  (HDIM / KS)         // 512
#define TM      256                 // tokens per block
#define BK      32                  // K chunk staged in LDS
#define XS_ST   260                 // 256 tokens + 4 pad (keeps 16B row alignment)
#define WS_ST   68                  // 64 experts + 4 pad

// ---------------------------------------------------------------------------
// GEMM: partial[ks][t][e] = sum_{k in slice ks} x[t][k] * w[e][k]
// Block: 256 threads, TM=256 tokens x 64 experts, K range = 512.
// Per-thread register tile: 8 tokens x 8 experts (1.0 LDS-byte/FMA -> VALU-bound).
// ---------------------------------------------------------------------------
__global__ __launch_bounds__(256, 3)
void router_gemm_kernel(const float* __restrict__ x,
                        const float* __restrict__ w,
                        float* __restrict__ partial)
{
    __shared__ float Xs[BK][XS_ST];   // [k][token]  33,280 B
    __shared__ float Ws[BK][WS_ST];   // [k][expert]  8,704 B

    const int tid = threadIdx.x;
    const int tb  = blockIdx.x & 63;   // token block (64 blocks of 256 tokens)
    const int ks  = blockIdx.x >> 6;   // k-slice 0..3
    const int t0  = tb * TM;
    const int k0  = ks * KSLICE;

    const int kq  = tid & 7;           // k-quad for staging (kq*4 .. kq*4+3)
    const int rr  = tid >> 3;          // row for staging (0..31)

    const int ex8 = (tid & 7) * 8;     // this thread's 8 experts
    const int ty8 = (tid >> 3) * 8;    // this thread's 8 tokens

    float acc[8][8];
#pragma unroll
    for (int i = 0; i < 8; ++i)
#pragma unroll
        for (int j = 0; j < 8; ++j) acc[i][j] = 0.0f;

    for (int kc = 0; kc < KSLICE; kc += BK) {
        __syncthreads();   // previous chunk's compute done before overwrite

        // stage X tile: 256 tokens x 32 k  (transposed into [k][token])
        {
            const float* xg = x + (size_t)t0 * HDIM + (k0 + kc) + kq * 4;
#pragma unroll
            for (int p = 0; p < 8; ++p) {
                const int r = p * 32 + rr;
                const float4 v = *(const float4*)(xg + (size_t)r * HDIM);
                Xs[kq * 4 + 0][r] = v.x;
                Xs[kq * 4 + 1][r] = v.y;
                Xs[kq * 4 + 2][r] = v.z;
                Xs[kq * 4 + 3][r] = v.w;
            }
        }
        // stage W tile: 64 experts x 32 k  (transposed into [k][expert])
        {
            const float* wg = w + (k0 + kc) + kq * 4;
#pragma unroll
            for (int p = 0; p < 2; ++p) {
                const int e = p * 32 + rr;
                const float4 v = *(const float4*)(wg + (size_t)e * HDIM);
                Ws[kq * 4 + 0][e] = v.x;
                Ws[kq * 4 + 1][e] = v.y;
                Ws[kq * 4 + 2][e] = v.z;
                Ws[kq * 4 + 3][e] = v.w;
            }
        }
        __syncthreads();

#pragma unroll 4
        for (int k = 0; k < BK; ++k) {
            float xv[8], wv[8];
            *(float4*)&xv[0] = *(const float4*)&Xs[k][ty8];
            *(float4*)&xv[4] = *(const float4*)&Xs[k][ty8 + 4];
            *(float4*)&wv[0] = *(const float4*)&Ws[k][ex8];
            *(float4*)&wv[4] = *(const float4*)&Ws[k][ex8 + 4];
#pragma unroll
            for (int i = 0; i < 8; ++i)
#pragma unroll
                for (int j = 0; j < 8; ++j)
                    acc[i][j] = fmaf(xv[i], wv[j], acc[i][j]);
        }
    }

    // write partial logits: partial[ks][t][e]
    float* pp = partial + ((size_t)ks * T_TOTAL + t0) * NEXP;
#pragma unroll
    for (int i = 0; i < 8; ++i) {
        const int t = ty8 + i;
        const float4 s0 = make_float4(acc[i][0], acc[i][1], acc[i][2], acc[i][3]);
        const float4 s1 = make_float4(acc[i][4], acc[i][5], acc[i][6], acc[i][7]);
        *(float4*)(pp + (size_t)t * NEXP + ex8)     = s0;
        *(float4*)(pp + (size_t)t * NEXP + ex8 + 4) = s1;
    }
}

// ---------------------------------------------------------------------------
// Sigmoid + biased top-8 (desc, ties -> lower index) + renorm * 2.5.
// One wave per token, lane = expert.
// ---------------------------------------------------------------------------
__global__ __launch_bounds__(256)
void router_topk_kernel(const float* __restrict__ partial,
                        const float* __restrict__ bias,
                        float* __restrict__ out_scores,
                        float* __restrict__ out_idx)
{
    const int gid   = blockIdx.x * 256 + threadIdx.x;
    const int token = gid >> 6;
    const int lane  = threadIdx.x & 63;
    if (token >= T_TOTAL) return;

    const size_t base = (size_t)token * NEXP + lane;
    const size_t sl   = (size_t)T_TOTAL * NEXP;
    const float logit = partial[base] + partial[sl + base] +
                        partial[2 * sl + base] + partial[3 * sl + base];

    const float score = 1.0f / (1.0f + expf(-logit));
    float key = score + bias[lane];

    float myscore = 0.0f;
    int   myidx   = 0;
    float denom   = 0.0f;

#pragma unroll
    for (int r = 0; r < 8; ++r) {
        // wave-wide argmax on (key, idx), tie-break: lower idx (matches lax.top_k)
        float bk = key;
        int   bi = lane;
#pragma unroll
        for (int off = 32; off > 0; off >>= 1) {
            const float ok = __shfl_xor(bk, off);
            const int   oi = __shfl_xor(bi, off);
            if (ok > bk || (ok == bk && oi < bi)) { bk = ok; bi = oi; }
        }
        const float wsc = __shfl(score, bi);   // raw (unbiased) score of winner
        denom += wsc;
        if (lane == r)  { myscore = wsc; myidx = bi; }
        if (lane == bi) key = -__builtin_inff();   // remove winner
    }

    const float factor = 2.5f / (denom + 1e-20f);
    if (lane < 8) {
        out_scores[(size_t)token * 8 + lane] = myscore * factor;
        out_idx  [(size_t)token * 8 + lane] = (float)myidx;  // int value as f32
    }
}

// ---------------------------------------------------------------------------
extern "C" void kernel_launch(void* const* d_in, const int* in_sizes, int n_in,
                              void* d_out, int out_size, void* d_ws, size_t ws_size,
                              hipStream_t stream)
{
    const float* x    = (const float*)d_in[0];   // hidden_states [4,4096,2048]
    const float* bias = (const float*)d_in[1];   // expert_bias   [64]
    const float* w    = (const float*)d_in[2];   // gate_w        [64,2048]

    float* out     = (float*)d_out;              // [T*8 scores | T*8 indices]
    float* partial = (float*)d_ws;               // KS*T*E*4 = 16 MiB scratch

    router_gemm_kernel<<<dim3(64 * KS), dim3(256), 0, stream>>>(x, w, partial);
    router_topk_kernel<<<dim3(T_TOTAL * 64 / 256), dim3(256), 0, stream>>>(
        partial, bias, out, out + (size_t)T_TOTAL * 8);
}